// Round 1
// baseline (2962.353 us; speedup 1.0000x reference)
//
#include <hip/hip_runtime.h>

#define N_NODES 100000
#define N_EDGES 1600000
#define N_LABEL 200000
#define HID 128
#define OUT 5

// ---------------------------------------------------------------------------
// K1: xw = x @ W   (fp32, vector ALU; W resident in LDS, 16-row tiles,
//     each thread computes 4 rows x 4 cols with float4 LDS reads)
// ---------------------------------------------------------------------------
#define K1_ROWS 16
__global__ __launch_bounds__(128) void k_gemm(const float* __restrict__ x,
                                              const float* __restrict__ Wg,
                                              float* __restrict__ xw) {
    __shared__ float Wl[HID * HID];      // 64 KB
    __shared__ float xs[K1_ROWS * HID];  // 8 KB
    const int tid = threadIdx.x;

    {   // load W: 16384 floats = 4096 float4, 32 per thread
        const float4* W4 = (const float4*)Wg;
        float4* Wl4 = (float4*)Wl;
#pragma unroll
        for (int i = 0; i < 32; ++i) Wl4[i * 128 + tid] = W4[i * 128 + tid];
    }

    const int cq = tid & 31;   // col quad: cols 4*cq .. 4*cq+3
    const int rg = tid >> 5;   // row group: rows rg*4 .. rg*4+3 within tile
    const int ntiles = N_NODES / K1_ROWS;  // 6250

    for (int t = blockIdx.x; t < ntiles; t += gridDim.x) {
        const int r0 = t * K1_ROWS;
        __syncthreads();   // protect xs from previous tile (also covers W load)
        {   // load 16 rows of x: 2048 floats = 512 float4, 4 per thread
            const float4* xg = (const float4*)(x + (size_t)r0 * HID);
            float4* xs4 = (float4*)xs;
#pragma unroll
            for (int i = 0; i < 4; ++i) xs4[i * 128 + tid] = xg[i * 128 + tid];
        }
        __syncthreads();

        float acc[4][4];
#pragma unroll
        for (int j = 0; j < 4; ++j)
#pragma unroll
            for (int c = 0; c < 4; ++c) acc[j][c] = 0.0f;

        for (int k = 0; k < HID; k += 4) {
            float4 wv[4];
#pragma unroll
            for (int kk = 0; kk < 4; ++kk)
                wv[kk] = *(const float4*)&Wl[(k + kk) * HID + 4 * cq];
#pragma unroll
            for (int j = 0; j < 4; ++j) {
                float4 xv = *(const float4*)&xs[(rg * 4 + j) * HID + k];
                acc[j][0] += xv.x * wv[0].x + xv.y * wv[1].x + xv.z * wv[2].x + xv.w * wv[3].x;
                acc[j][1] += xv.x * wv[0].y + xv.y * wv[1].y + xv.z * wv[2].y + xv.w * wv[3].y;
                acc[j][2] += xv.x * wv[0].z + xv.y * wv[1].z + xv.z * wv[2].z + xv.w * wv[3].z;
                acc[j][3] += xv.x * wv[0].w + xv.y * wv[1].w + xv.z * wv[2].w + xv.w * wv[3].w;
            }
        }
#pragma unroll
        for (int j = 0; j < 4; ++j) {
            float4 o;
            o.x = acc[j][0]; o.y = acc[j][1]; o.z = acc[j][2]; o.w = acc[j][3];
            *(float4*)&xw[(size_t)(r0 + rg * 4 + j) * HID + 4 * cq] = o;
        }
    }
}

// ---------------------------------------------------------------------------
// K2a: deg[i] = 1.0 (self-loop)
// ---------------------------------------------------------------------------
__global__ void k_deg_init(float* __restrict__ deg) {
    int i = blockIdx.x * 256 + threadIdx.x;
    if (i < N_NODES) deg[i] = 1.0f;
}

// K2b: deg[dst] += 1 per edge
__global__ void k_deg(const int* __restrict__ ei, float* __restrict__ deg) {
    int e = blockIdx.x * 256 + threadIdx.x;
    if (e < N_EDGES) {
        int dst = ei[N_EDGES + e];
        unsafeAtomicAdd(&deg[dst], 1.0f);
    }
}

// K2c: dinv[n] = rsqrt(deg[n]); h[n][:] = xw[n][:] * dinv^2 + b  (self-loop + bias)
__global__ __launch_bounds__(128) void k_init_h(const float* __restrict__ xw,
                                                const float* __restrict__ deg,
                                                const float* __restrict__ b,
                                                float* __restrict__ dinv,
                                                float* __restrict__ h) {
    const int n = blockIdx.x;
    const int t = threadIdx.x;
    float d = deg[n];               // always >= 1
    float di = rsqrtf(d);
    if (t == 0) dinv[n] = di;
    size_t idx = (size_t)n * HID + t;
    h[idx] = xw[idx] * (di * di) + b[t];
}

// ---------------------------------------------------------------------------
// K3: scatter  h[dst] += xw[src] * dinv[src]*dinv[dst]
//     32 lanes per edge, float4 per lane, HW fp32 atomics
// ---------------------------------------------------------------------------
__global__ __launch_bounds__(256) void k_scatter(const int* __restrict__ ei,
                                                 const float* __restrict__ xw,
                                                 const float* __restrict__ dinv,
                                                 float* __restrict__ h) {
    long long gid = (long long)blockIdx.x * 256 + threadIdx.x;
    int e = (int)(gid >> 5);
    int q = (int)(gid & 31);
    if (e >= N_EDGES) return;
    int src = ei[e];
    int dst = ei[N_EDGES + e];
    float nv = dinv[src] * dinv[dst];
    float4 v = ((const float4*)xw)[src * 32 + q];
    float* hp = h + (size_t)dst * HID + q * 4;
    unsafeAtomicAdd(hp + 0, v.x * nv);
    unsafeAtomicAdd(hp + 1, v.y * nv);
    unsafeAtomicAdd(hp + 2, v.z * nv);
    unsafeAtomicAdd(hp + 3, v.w * nv);
}

// ---------------------------------------------------------------------------
// K4: out[l] = concat(h[eli0[l]], h[eli1[l]]) @ W_lin + b_lin
//     one wave per label edge; W_lin (2*HID x OUT) in LDS
// ---------------------------------------------------------------------------
__global__ __launch_bounds__(256) void k_link(const int* __restrict__ eli,
                                              const float* __restrict__ h,
                                              const float* __restrict__ Wg,
                                              const float* __restrict__ bl,
                                              float* __restrict__ out) {
    __shared__ float Wl[2 * HID * OUT];  // 1280 floats
    __shared__ float bls[OUT];
    const int tid = threadIdx.x;
    for (int i = tid; i < 2 * HID * OUT; i += 256) Wl[i] = Wg[i];
    if (tid < OUT) bls[tid] = bl[tid];
    __syncthreads();

    const int wid = tid >> 6;
    const int lane = tid & 63;
    const int l = blockIdx.x * 4 + wid;
    if (l >= N_LABEL) return;

    const int d = eli[l];
    const int p = eli[N_LABEL + l];
    const float* hd = h + (size_t)d * HID;
    const float* hp = h + (size_t)p * HID;

    float acc[OUT] = {0.f, 0.f, 0.f, 0.f, 0.f};
#pragma unroll
    for (int j = 0; j < 2; ++j) {          // drug half: k = j*64 + lane in [0,128)
        int k = j * 64 + lane;
        float hv = hd[k];
        const float* wr = &Wl[k * OUT];
#pragma unroll
        for (int o = 0; o < OUT; ++o) acc[o] += hv * wr[o];
    }
#pragma unroll
    for (int j = 0; j < 2; ++j) {          // prot half: k = 128 + j*64 + lane
        int k = j * 64 + lane;
        float hv = hp[k];
        const float* wr = &Wl[(HID + k) * OUT];
#pragma unroll
        for (int o = 0; o < OUT; ++o) acc[o] += hv * wr[o];
    }

#pragma unroll
    for (int o = 0; o < OUT; ++o) {
        float a = acc[o];
#pragma unroll
        for (int off = 32; off > 0; off >>= 1) a += __shfl_xor(a, off);
        if (lane == 0) out[(size_t)l * OUT + o] = a + bls[o];
    }
}

// ---------------------------------------------------------------------------
extern "C" void kernel_launch(void* const* d_in, const int* in_sizes, int n_in,
                              void* d_out, int out_size, void* d_ws, size_t ws_size,
                              hipStream_t stream) {
    const float* x     = (const float*)d_in[0];
    const int*   ei    = (const int*)d_in[1];
    const int*   eli   = (const int*)d_in[2];
    const float* W_gcn = (const float*)d_in[3];
    const float* b_gcn = (const float*)d_in[4];
    const float* W_lin = (const float*)d_in[5];
    const float* b_lin = (const float*)d_in[6];
    float* out = (float*)d_out;

    float* xw   = (float*)d_ws;                       // 12.8M floats
    float* h    = xw + (size_t)N_NODES * HID;         // 12.8M floats
    float* deg  = h + (size_t)N_NODES * HID;          // 100k floats
    float* dinv = deg + N_NODES;                      // 100k floats

    // K1: xw = x @ W_gcn
    k_gemm<<<1000, 128, 0, stream>>>(x, W_gcn, xw);
    // K2a: deg = 1 (self-loops)
    k_deg_init<<<(N_NODES + 255) / 256, 256, 0, stream>>>(deg);
    // K2b: deg[dst] += 1
    k_deg<<<(N_EDGES + 255) / 256, 256, 0, stream>>>(ei, deg);
    // K2c: dinv + h init (self-loop message + bias)
    k_init_h<<<N_NODES, 128, 0, stream>>>(xw, deg, b_gcn, dinv, h);
    // K3: edge scatter with fp32 HW atomics
    k_scatter<<<(int)(((long long)N_EDGES * 32 + 255) / 256), 256, 0, stream>>>(ei, xw, dinv, h);
    // K4: link prediction head
    k_link<<<(N_LABEL + 3) / 4, 256, 0, stream>>>(eli, h, W_lin, b_lin, out);
}

// Round 2
// 728.597 us; speedup vs baseline: 4.0658x; 4.0658x over previous
//
#include <hip/hip_runtime.h>

#define N_NODES 100000
#define N_EDGES 1600000
#define N_LABEL 200000
#define HID 128
#define OUT 5

// ---------------------------------------------------------------------------
// K1: xw = x @ W   (fp32 vector ALU; W resident in LDS, 16-row tiles,
//     each thread computes 4 rows x 4 cols with float4 LDS reads)
// ---------------------------------------------------------------------------
#define K1_ROWS 16
__global__ __launch_bounds__(128) void k_gemm(const float* __restrict__ x,
                                              const float* __restrict__ Wg,
                                              float* __restrict__ xw) {
    __shared__ float Wl[HID * HID];      // 64 KB
    __shared__ float xs[K1_ROWS * HID];  // 8 KB
    const int tid = threadIdx.x;

    {   // load W: 16384 floats = 4096 float4, 32 per thread
        const float4* W4 = (const float4*)Wg;
        float4* Wl4 = (float4*)Wl;
#pragma unroll
        for (int i = 0; i < 32; ++i) Wl4[i * 128 + tid] = W4[i * 128 + tid];
    }

    const int cq = tid & 31;   // col quad: cols 4*cq .. 4*cq+3
    const int rg = tid >> 5;   // row group: rows rg*4 .. rg*4+3 within tile
    const int ntiles = N_NODES / K1_ROWS;  // 6250

    for (int t = blockIdx.x; t < ntiles; t += gridDim.x) {
        const int r0 = t * K1_ROWS;
        __syncthreads();   // protect xs from previous tile (also covers W load)
        {   // load 16 rows of x: 2048 floats = 512 float4, 4 per thread
            const float4* xg = (const float4*)(x + (size_t)r0 * HID);
            float4* xs4 = (float4*)xs;
#pragma unroll
            for (int i = 0; i < 4; ++i) xs4[i * 128 + tid] = xg[i * 128 + tid];
        }
        __syncthreads();

        float acc[4][4];
#pragma unroll
        for (int j = 0; j < 4; ++j)
#pragma unroll
            for (int c = 0; c < 4; ++c) acc[j][c] = 0.0f;

        for (int k = 0; k < HID; k += 4) {
            float4 wv[4];
#pragma unroll
            for (int kk = 0; kk < 4; ++kk)
                wv[kk] = *(const float4*)&Wl[(k + kk) * HID + 4 * cq];
#pragma unroll
            for (int j = 0; j < 4; ++j) {
                float4 xv = *(const float4*)&xs[(rg * 4 + j) * HID + k];
                acc[j][0] += xv.x * wv[0].x + xv.y * wv[1].x + xv.z * wv[2].x + xv.w * wv[3].x;
                acc[j][1] += xv.x * wv[0].y + xv.y * wv[1].y + xv.z * wv[2].y + xv.w * wv[3].y;
                acc[j][2] += xv.x * wv[0].z + xv.y * wv[1].z + xv.z * wv[2].z + xv.w * wv[3].z;
                acc[j][3] += xv.x * wv[0].w + xv.y * wv[1].w + xv.z * wv[2].w + xv.w * wv[3].w;
            }
        }
#pragma unroll
        for (int j = 0; j < 4; ++j) {
            float4 o;
            o.x = acc[j][0]; o.y = acc[j][1]; o.z = acc[j][2]; o.w = acc[j][3];
            *(float4*)&xw[(size_t)(r0 + rg * 4 + j) * HID + 4 * cq] = o;
        }
    }
}

// ---------------------------------------------------------------------------
// K2: count[dst]++ per edge (int atomics)
// ---------------------------------------------------------------------------
__global__ void k_count(const int* __restrict__ ei, int* __restrict__ count) {
    int e = blockIdx.x * 256 + threadIdx.x;
    if (e < N_EDGES) atomicAdd(&count[ei[N_EDGES + e]], 1);
}

// ---------------------------------------------------------------------------
// K3: single-block exclusive prefix sum over count -> row_start[N+1];
//     also dinv[i] = rsqrt(count[i]+1) and cursor[i] = 0
// ---------------------------------------------------------------------------
#define SCAN_T 1024
__global__ __launch_bounds__(SCAN_T) void k_scan(const int* __restrict__ count,
                                                 int* __restrict__ row_start,
                                                 int* __restrict__ cursor,
                                                 float* __restrict__ dinv) {
    __shared__ int part[SCAN_T];
    const int t = threadIdx.x;
    const int chunk = (N_NODES + SCAN_T - 1) / SCAN_T;  // 98
    const int lo = t * chunk;
    const int hi = min(lo + chunk, N_NODES);
    int s = 0;
    for (int i = lo; i < hi; ++i) s += count[i];
    part[t] = s;
    __syncthreads();
    for (int off = 1; off < SCAN_T; off <<= 1) {
        int add = (t >= off) ? part[t - off] : 0;
        __syncthreads();
        part[t] += add;
        __syncthreads();
    }
    int run = part[t] - s;  // exclusive prefix at lo
    for (int i = lo; i < hi; ++i) {
        int c = count[i];
        row_start[i] = run;
        run += c;
        cursor[i] = 0;
        dinv[i] = rsqrtf((float)(c + 1));
    }
    if (t == SCAN_T - 1) row_start[N_NODES] = run;  // == N_EDGES
}

// ---------------------------------------------------------------------------
// K4: fill CSR buckets: csr[row_start[dst] + cursor[dst]++] = src
// ---------------------------------------------------------------------------
__global__ void k_fill(const int* __restrict__ ei, const int* __restrict__ row_start,
                       int* __restrict__ cursor, int* __restrict__ csr) {
    int e = blockIdx.x * 256 + threadIdx.x;
    if (e < N_EDGES) {
        int src = ei[e];
        int dst = ei[N_EDGES + e];
        int pos = row_start[dst] + atomicAdd(&cursor[dst], 1);
        csr[pos] = src;
    }
}

// ---------------------------------------------------------------------------
// K5: pull-aggregate. 32 lanes per node, float4 per lane.
//     h[n] = sum_{src in in(n)} xw[src]*dinv[src]*dinv[n]
//            + xw[n]*dinv[n]^2 + b
// ---------------------------------------------------------------------------
__global__ __launch_bounds__(256) void k_pull(const float* __restrict__ xw,
                                              const int* __restrict__ row_start,
                                              const int* __restrict__ csr,
                                              const float* __restrict__ dinv,
                                              const float* __restrict__ b,
                                              float* __restrict__ h) {
    int gid = blockIdx.x * 256 + threadIdx.x;
    int n = gid >> 5;
    int q = gid & 31;
    if (n >= N_NODES) return;

    const float4* xw4 = (const float4*)xw;
    float di = dinv[n];
    float4 v = xw4[(size_t)n * 32 + q];
    float s = di * di;
    float4 acc;
    acc.x = v.x * s; acc.y = v.y * s; acc.z = v.z * s; acc.w = v.w * s;

    int beg = row_start[n];
    int end = row_start[n + 1];
    for (int i = beg; i < end; ++i) {
        int src = csr[i];
        float nv = dinv[src] * di;
        float4 m = xw4[(size_t)src * 32 + q];
        acc.x += m.x * nv; acc.y += m.y * nv; acc.z += m.z * nv; acc.w += m.w * nv;
    }
    float4 bv = ((const float4*)b)[q];
    acc.x += bv.x; acc.y += bv.y; acc.z += bv.z; acc.w += bv.w;
    ((float4*)h)[(size_t)n * 32 + q] = acc;
}

// ---------------------------------------------------------------------------
// K6: out[l] = concat(h[eli0[l]], h[eli1[l]]) @ W_lin + b_lin
//     one wave per label edge; W_lin (2*HID x OUT) in LDS
// ---------------------------------------------------------------------------
__global__ __launch_bounds__(256) void k_link(const int* __restrict__ eli,
                                              const float* __restrict__ h,
                                              const float* __restrict__ Wg,
                                              const float* __restrict__ bl,
                                              float* __restrict__ out) {
    __shared__ float Wl[2 * HID * OUT];  // 1280 floats
    __shared__ float bls[OUT];
    const int tid = threadIdx.x;
    for (int i = tid; i < 2 * HID * OUT; i += 256) Wl[i] = Wg[i];
    if (tid < OUT) bls[tid] = bl[tid];
    __syncthreads();

    const int wid = tid >> 6;
    const int lane = tid & 63;
    const int l = blockIdx.x * 4 + wid;
    if (l >= N_LABEL) return;

    const int d = eli[l];
    const int p = eli[N_LABEL + l];
    const float* hd = h + (size_t)d * HID;
    const float* hp = h + (size_t)p * HID;

    float acc[OUT] = {0.f, 0.f, 0.f, 0.f, 0.f};
#pragma unroll
    for (int j = 0; j < 2; ++j) {          // drug half
        int k = j * 64 + lane;
        float hv = hd[k];
        const float* wr = &Wl[k * OUT];
#pragma unroll
        for (int o = 0; o < OUT; ++o) acc[o] += hv * wr[o];
    }
#pragma unroll
    for (int j = 0; j < 2; ++j) {          // prot half
        int k = j * 64 + lane;
        float hv = hp[k];
        const float* wr = &Wl[(HID + k) * OUT];
#pragma unroll
        for (int o = 0; o < OUT; ++o) acc[o] += hv * wr[o];
    }

#pragma unroll
    for (int o = 0; o < OUT; ++o) {
        float a = acc[o];
#pragma unroll
        for (int off = 32; off > 0; off >>= 1) a += __shfl_xor(a, off);
        if (lane == 0) out[(size_t)l * OUT + o] = a + bls[o];
    }
}

// ---------------------------------------------------------------------------
extern "C" void kernel_launch(void* const* d_in, const int* in_sizes, int n_in,
                              void* d_out, int out_size, void* d_ws, size_t ws_size,
                              hipStream_t stream) {
    const float* x     = (const float*)d_in[0];
    const int*   ei    = (const int*)d_in[1];
    const int*   eli   = (const int*)d_in[2];
    const float* W_gcn = (const float*)d_in[3];
    const float* b_gcn = (const float*)d_in[4];
    const float* W_lin = (const float*)d_in[5];
    const float* b_lin = (const float*)d_in[6];
    float* out = (float*)d_out;

    // workspace layout
    float* xw        = (float*)d_ws;                          // 12.8M floats (51.2 MB)
    float* h         = xw + (size_t)N_NODES * HID;            // 12.8M floats (51.2 MB)
    float* dinv      = h + (size_t)N_NODES * HID;             // 100k floats
    int*   count     = (int*)(dinv + N_NODES);                // 100k ints
    int*   cursor    = count + N_NODES;                       // 100k ints
    int*   row_start = cursor + N_NODES;                      // 100k+1 ints
    int*   csr       = row_start + (N_NODES + 1);             // 1.6M ints (6.4 MB)

    hipMemsetAsync(count, 0, N_NODES * sizeof(int), stream);

    // K1: xw = x @ W_gcn
    k_gemm<<<1000, 128, 0, stream>>>(x, W_gcn, xw);
    // K2: in-degree count (int atomics)
    k_count<<<(N_EDGES + 255) / 256, 256, 0, stream>>>(ei, count);
    // K3: prefix sum -> row_start; dinv; cursor=0
    k_scan<<<1, SCAN_T, 0, stream>>>(count, row_start, cursor, dinv);
    // K4: CSR fill
    k_fill<<<(N_EDGES + 255) / 256, 256, 0, stream>>>(ei, row_start, cursor, csr);
    // K5: pull aggregation (self-loop + bias fused)
    k_pull<<<(N_NODES * 32 + 255) / 256, 256, 0, stream>>>(xw, row_start, csr, dinv, b_gcn, h);
    // K6: link prediction head
    k_link<<<(N_LABEL + 3) / 4, 256, 0, stream>>>(eli, h, W_lin, b_lin, out);
}

// Round 3
// 493.309 us; speedup vs baseline: 6.0051x; 1.4770x over previous
//
#include <hip/hip_runtime.h>

#define N_NODES 100000
#define N_EDGES 1600000
#define N_LABEL 200000
#define HID 128
#define OUT 5

// ---------------------------------------------------------------------------
// K1: xw = x @ W   (fp32 vector ALU; W resident in LDS, 16-row tiles,
//     each thread computes 4 rows x 4 cols with float4 LDS reads)
// ---------------------------------------------------------------------------
#define K1_ROWS 16
__global__ __launch_bounds__(128) void k_gemm(const float* __restrict__ x,
                                              const float* __restrict__ Wg,
                                              float* __restrict__ xw) {
    __shared__ float Wl[HID * HID];      // 64 KB
    __shared__ float xs[K1_ROWS * HID];  // 8 KB
    const int tid = threadIdx.x;

    {   // load W: 16384 floats = 4096 float4, 32 per thread
        const float4* W4 = (const float4*)Wg;
        float4* Wl4 = (float4*)Wl;
#pragma unroll
        for (int i = 0; i < 32; ++i) Wl4[i * 128 + tid] = W4[i * 128 + tid];
    }

    const int cq = tid & 31;   // col quad: cols 4*cq .. 4*cq+3
    const int rg = tid >> 5;   // row group: rows rg*4 .. rg*4+3 within tile
    const int ntiles = N_NODES / K1_ROWS;  // 6250

    for (int t = blockIdx.x; t < ntiles; t += gridDim.x) {
        const int r0 = t * K1_ROWS;
        __syncthreads();   // protect xs from previous tile (also covers W load)
        {   // load 16 rows of x: 2048 floats = 512 float4, 4 per thread
            const float4* xg = (const float4*)(x + (size_t)r0 * HID);
            float4* xs4 = (float4*)xs;
#pragma unroll
            for (int i = 0; i < 4; ++i) xs4[i * 128 + tid] = xg[i * 128 + tid];
        }
        __syncthreads();

        float acc[4][4];
#pragma unroll
        for (int j = 0; j < 4; ++j)
#pragma unroll
            for (int c = 0; c < 4; ++c) acc[j][c] = 0.0f;

        for (int k = 0; k < HID; k += 4) {
            float4 wv[4];
#pragma unroll
            for (int kk = 0; kk < 4; ++kk)
                wv[kk] = *(const float4*)&Wl[(k + kk) * HID + 4 * cq];
#pragma unroll
            for (int j = 0; j < 4; ++j) {
                float4 xv = *(const float4*)&xs[(rg * 4 + j) * HID + k];
                acc[j][0] += xv.x * wv[0].x + xv.y * wv[1].x + xv.z * wv[2].x + xv.w * wv[3].x;
                acc[j][1] += xv.x * wv[0].y + xv.y * wv[1].y + xv.z * wv[2].y + xv.w * wv[3].y;
                acc[j][2] += xv.x * wv[0].z + xv.y * wv[1].z + xv.z * wv[2].z + xv.w * wv[3].z;
                acc[j][3] += xv.x * wv[0].w + xv.y * wv[1].w + xv.z * wv[2].w + xv.w * wv[3].w;
            }
        }
#pragma unroll
        for (int j = 0; j < 4; ++j) {
            float4 o;
            o.x = acc[j][0]; o.y = acc[j][1]; o.z = acc[j][2]; o.w = acc[j][3];
            *(float4*)&xw[(size_t)(r0 + rg * 4 + j) * HID + 4 * cq] = o;
        }
    }
}

// ---------------------------------------------------------------------------
// K2: count[dst]++ per edge (int atomics)
// ---------------------------------------------------------------------------
__global__ void k_count(const int* __restrict__ ei, int* __restrict__ count) {
    int e = blockIdx.x * 256 + threadIdx.x;
    if (e < N_EDGES) atomicAdd(&count[ei[N_EDGES + e]], 1);
}

// ---------------------------------------------------------------------------
// K3: CSR range allocator (replaces global prefix scan).
//     Buckets need only be DISJOINT, not ordered: each 256-block scans its
//     counts in LDS, grabs a global base with ONE atomicAdd, assigns
//     row_start[i] = base + excl_prefix. Also dinv[i] = rsqrt(c+1), cursor=0.
// ---------------------------------------------------------------------------
__global__ __launch_bounds__(256) void k_alloc(const int* __restrict__ count,
                                               int* __restrict__ row_start,
                                               int* __restrict__ cursor,
                                               float* __restrict__ dinv,
                                               int* __restrict__ total) {
    __shared__ int sm[256];
    __shared__ int base;
    const int t = threadIdx.x;
    const int i = blockIdx.x * 256 + t;
    int c = (i < N_NODES) ? count[i] : 0;
    sm[t] = c;
    __syncthreads();
#pragma unroll
    for (int off = 1; off < 256; off <<= 1) {
        int v = (t >= off) ? sm[t - off] : 0;
        __syncthreads();
        sm[t] += v;
        __syncthreads();
    }
    if (t == 255) base = atomicAdd(total, sm[255]);
    int incl = sm[t];
    __syncthreads();
    if (i < N_NODES) {
        row_start[i] = base + incl - c;
        cursor[i] = 0;
        dinv[i] = rsqrtf((float)(c + 1));
    }
}

// ---------------------------------------------------------------------------
// K4: fill CSR buckets: csr[row_start[dst] + cursor[dst]++] = src
// ---------------------------------------------------------------------------
__global__ void k_fill(const int* __restrict__ ei, const int* __restrict__ row_start,
                       int* __restrict__ cursor, int* __restrict__ csr) {
    int e = blockIdx.x * 256 + threadIdx.x;
    if (e < N_EDGES) {
        int src = ei[e];
        int dst = ei[N_EDGES + e];
        int pos = row_start[dst] + atomicAdd(&cursor[dst], 1);
        csr[pos] = src;
    }
}

// ---------------------------------------------------------------------------
// K5: pull-aggregate. 32 lanes per node, float4 per lane.
//     h[n] = sum_{src in in(n)} xw[src]*dinv[src]*dinv[n]
//            + xw[n]*dinv[n]^2 + b      (end = beg + count[n])
// ---------------------------------------------------------------------------
__global__ __launch_bounds__(256) void k_pull(const float* __restrict__ xw,
                                              const int* __restrict__ row_start,
                                              const int* __restrict__ count,
                                              const int* __restrict__ csr,
                                              const float* __restrict__ dinv,
                                              const float* __restrict__ b,
                                              float* __restrict__ h) {
    int gid = blockIdx.x * 256 + threadIdx.x;
    int n = gid >> 5;
    int q = gid & 31;
    if (n >= N_NODES) return;

    const float4* xw4 = (const float4*)xw;
    float di = dinv[n];
    float4 v = xw4[(size_t)n * 32 + q];
    float s = di * di;
    float4 acc;
    acc.x = v.x * s; acc.y = v.y * s; acc.z = v.z * s; acc.w = v.w * s;

    int beg = row_start[n];
    int end = beg + count[n];
    for (int i = beg; i < end; ++i) {
        int src = csr[i];
        float nv = dinv[src] * di;
        float4 m = xw4[(size_t)src * 32 + q];
        acc.x += m.x * nv; acc.y += m.y * nv; acc.z += m.z * nv; acc.w += m.w * nv;
    }
    float4 bv = ((const float4*)b)[q];
    acc.x += bv.x; acc.y += bv.y; acc.z += bv.z; acc.w += bv.w;
    ((float4*)h)[(size_t)n * 32 + q] = acc;
}

// ---------------------------------------------------------------------------
// K6: out[l] = concat(h[eli0[l]], h[eli1[l]]) @ W_lin + b_lin
//     one wave per label edge; W_lin (2*HID x OUT) in LDS
// ---------------------------------------------------------------------------
__global__ __launch_bounds__(256) void k_link(const int* __restrict__ eli,
                                              const float* __restrict__ h,
                                              const float* __restrict__ Wg,
                                              const float* __restrict__ bl,
                                              float* __restrict__ out) {
    __shared__ float Wl[2 * HID * OUT];  // 1280 floats
    __shared__ float bls[OUT];
    const int tid = threadIdx.x;
    for (int i = tid; i < 2 * HID * OUT; i += 256) Wl[i] = Wg[i];
    if (tid < OUT) bls[tid] = bl[tid];
    __syncthreads();

    const int wid = tid >> 6;
    const int lane = tid & 63;
    const int l = blockIdx.x * 4 + wid;
    if (l >= N_LABEL) return;

    const int d = eli[l];
    const int p = eli[N_LABEL + l];
    const float* hd = h + (size_t)d * HID;
    const float* hp = h + (size_t)p * HID;

    float acc[OUT] = {0.f, 0.f, 0.f, 0.f, 0.f};
#pragma unroll
    for (int j = 0; j < 2; ++j) {          // drug half
        int k = j * 64 + lane;
        float hv = hd[k];
        const float* wr = &Wl[k * OUT];
#pragma unroll
        for (int o = 0; o < OUT; ++o) acc[o] += hv * wr[o];
    }
#pragma unroll
    for (int j = 0; j < 2; ++j) {          // prot half
        int k = j * 64 + lane;
        float hv = hp[k];
        const float* wr = &Wl[(HID + k) * OUT];
#pragma unroll
        for (int o = 0; o < OUT; ++o) acc[o] += hv * wr[o];
    }

#pragma unroll
    for (int o = 0; o < OUT; ++o) {
        float a = acc[o];
#pragma unroll
        for (int off = 32; off > 0; off >>= 1) a += __shfl_xor(a, off);
        if (lane == 0) out[(size_t)l * OUT + o] = a + bls[o];
    }
}

// ---------------------------------------------------------------------------
extern "C" void kernel_launch(void* const* d_in, const int* in_sizes, int n_in,
                              void* d_out, int out_size, void* d_ws, size_t ws_size,
                              hipStream_t stream) {
    const float* x     = (const float*)d_in[0];
    const int*   ei    = (const int*)d_in[1];
    const int*   eli   = (const int*)d_in[2];
    const float* W_gcn = (const float*)d_in[3];
    const float* b_gcn = (const float*)d_in[4];
    const float* W_lin = (const float*)d_in[5];
    const float* b_lin = (const float*)d_in[6];
    float* out = (float*)d_out;

    // workspace layout
    float* xw        = (float*)d_ws;                          // 12.8M floats (51.2 MB)
    float* h         = xw + (size_t)N_NODES * HID;            // 12.8M floats (51.2 MB)
    float* dinv      = h + (size_t)N_NODES * HID;             // 100k floats
    int*   count     = (int*)(dinv + N_NODES);                // 100k ints
    int*   cursor    = count + N_NODES;                       // 100k ints
    int*   row_start = cursor + N_NODES;                      // 100k ints
    int*   total     = row_start + N_NODES;                   // 1 int
    int*   csr       = total + 1;                             // 1.6M ints (6.4 MB)

    hipMemsetAsync(count, 0, N_NODES * sizeof(int), stream);
    hipMemsetAsync(total, 0, sizeof(int), stream);

    // K1: xw = x @ W_gcn
    k_gemm<<<1000, 128, 0, stream>>>(x, W_gcn, xw);
    // K2: in-degree count (int atomics)
    k_count<<<(N_EDGES + 255) / 256, 256, 0, stream>>>(ei, count);
    // K3: CSR range allocation + dinv + cursor reset
    k_alloc<<<(N_NODES + 255) / 256, 256, 0, stream>>>(count, row_start, cursor, dinv, total);
    // K4: CSR fill
    k_fill<<<(N_EDGES + 255) / 256, 256, 0, stream>>>(ei, row_start, cursor, csr);
    // K5: pull aggregation (self-loop + bias fused)
    k_pull<<<(N_NODES * 32 + 255) / 256, 256, 0, stream>>>(xw, row_start, count, csr, dinv, b_gcn, h);
    // K6: link prediction head
    k_link<<<(N_LABEL + 3) / 4, 256, 0, stream>>>(eli, h, W_lin, b_lin, out);
}

// Round 4
// 371.464 us; speedup vs baseline: 7.9748x; 1.3280x over previous
//
#include <hip/hip_runtime.h>

#define N_NODES 100000
#define N_EDGES 1600000
#define N_LABEL 200000
#define HID 128
#define OUT 5

// ---- bf16 helpers (manual, RNE) -------------------------------------------
__device__ inline void bf2x(unsigned u, float& lo, float& hi) {
    lo = __uint_as_float(u << 16);
    hi = __uint_as_float(u & 0xffff0000u);
}
__device__ inline unsigned pack2(float a, float b) {
    unsigned ua = __float_as_uint(a), ub = __float_as_uint(b);
    ua = (ua + 0x7fffu + ((ua >> 16) & 1u)) >> 16;
    ub = (ub + 0x7fffu + ((ub >> 16) & 1u)) & 0xffff0000u;
    return ua | ub;
}

// ---------------------------------------------------------------------------
// K1: xwh = bf16(x @ W)   (fp32 accumulate; W in LDS; 32-row tiles,
//     256 threads, each computes 4 rows x 4 cols)
// ---------------------------------------------------------------------------
#define K1_ROWS 32
__global__ __launch_bounds__(256) void k_gemm(const float* __restrict__ x,
                                              const float* __restrict__ Wg,
                                              unsigned* __restrict__ xwh) {
    __shared__ float Wl[HID * HID];      // 64 KB
    __shared__ float xs[K1_ROWS * HID];  // 16 KB
    const int tid = threadIdx.x;

    {   // load W: 4096 float4, 16 per thread
        const float4* W4 = (const float4*)Wg;
        float4* Wl4 = (float4*)Wl;
#pragma unroll
        for (int i = 0; i < 16; ++i) Wl4[i * 256 + tid] = W4[i * 256 + tid];
    }

    const int cq = tid & 31;   // col quad: cols 4*cq .. 4*cq+3
    const int rg = tid >> 5;   // row group: rows rg*4 .. rg*4+3 within tile
    const int ntiles = N_NODES / K1_ROWS;  // 3125

    for (int t = blockIdx.x; t < ntiles; t += gridDim.x) {
        const int r0 = t * K1_ROWS;
        __syncthreads();   // protect xs from previous tile (also covers W load)
        {   // load 32 rows of x: 1024 float4, 4 per thread
            const float4* xg = (const float4*)(x + (size_t)r0 * HID);
            float4* xs4 = (float4*)xs;
#pragma unroll
            for (int i = 0; i < 4; ++i) xs4[i * 256 + tid] = xg[i * 256 + tid];
        }
        __syncthreads();

        float acc[4][4];
#pragma unroll
        for (int j = 0; j < 4; ++j)
#pragma unroll
            for (int c = 0; c < 4; ++c) acc[j][c] = 0.0f;

        for (int k = 0; k < HID; k += 4) {
            float4 wv[4];
#pragma unroll
            for (int kk = 0; kk < 4; ++kk)
                wv[kk] = *(const float4*)&Wl[(k + kk) * HID + 4 * cq];
#pragma unroll
            for (int j = 0; j < 4; ++j) {
                float4 xv = *(const float4*)&xs[(rg * 4 + j) * HID + k];
                acc[j][0] += xv.x * wv[0].x + xv.y * wv[1].x + xv.z * wv[2].x + xv.w * wv[3].x;
                acc[j][1] += xv.x * wv[0].y + xv.y * wv[1].y + xv.z * wv[2].y + xv.w * wv[3].y;
                acc[j][2] += xv.x * wv[0].z + xv.y * wv[1].z + xv.z * wv[2].z + xv.w * wv[3].z;
                acc[j][3] += xv.x * wv[0].w + xv.y * wv[1].w + xv.z * wv[2].w + xv.w * wv[3].w;
            }
        }
#pragma unroll
        for (int j = 0; j < 4; ++j) {
            uint2 o;
            o.x = pack2(acc[j][0], acc[j][1]);
            o.y = pack2(acc[j][2], acc[j][3]);
            *(uint2*)(xwh + ((size_t)(r0 + rg * 4 + j) * HID + 4 * cq) / 2) = o;
        }
    }
}

// ---------------------------------------------------------------------------
// K2: count[dst]++ per edge (int atomics)
// ---------------------------------------------------------------------------
__global__ void k_count(const int* __restrict__ ei, int* __restrict__ count) {
    int e = blockIdx.x * 256 + threadIdx.x;
    if (e < N_EDGES) atomicAdd(&count[ei[N_EDGES + e]], 1);
}

// ---------------------------------------------------------------------------
// K3: CSR range allocator — buckets disjoint, not globally ordered.
// ---------------------------------------------------------------------------
__global__ __launch_bounds__(256) void k_alloc(const int* __restrict__ count,
                                               int* __restrict__ row_start,
                                               int* __restrict__ cursor,
                                               float* __restrict__ dinv,
                                               int* __restrict__ total) {
    __shared__ int sm[256];
    __shared__ int base;
    const int t = threadIdx.x;
    const int i = blockIdx.x * 256 + t;
    int c = (i < N_NODES) ? count[i] : 0;
    sm[t] = c;
    __syncthreads();
#pragma unroll
    for (int off = 1; off < 256; off <<= 1) {
        int v = (t >= off) ? sm[t - off] : 0;
        __syncthreads();
        sm[t] += v;
        __syncthreads();
    }
    if (t == 255) base = atomicAdd(total, sm[255]);
    int incl = sm[t];
    __syncthreads();
    if (i < N_NODES) {
        row_start[i] = base + incl - c;
        cursor[i] = 0;
        dinv[i] = rsqrtf((float)(c + 1));
    }
}

// ---------------------------------------------------------------------------
// K4: fill CSR buckets: csr[row_start[dst] + cursor[dst]++] = src
// ---------------------------------------------------------------------------
__global__ void k_fill(const int* __restrict__ ei, const int* __restrict__ row_start,
                       int* __restrict__ cursor, int* __restrict__ csr) {
    int e = blockIdx.x * 256 + threadIdx.x;
    if (e < N_EDGES) {
        int src = ei[e];
        int dst = ei[N_EDGES + e];
        int pos = row_start[dst] + atomicAdd(&cursor[dst], 1);
        csr[pos] = src;
    }
}

// ---------------------------------------------------------------------------
// K5: pull-aggregate (bf16 messages, fp32 accum). 16 lanes/node, 8 bf16/lane.
//     h16[n] = bf16( sum_in xwh[src]*dinv[src]*dinv[n] + xwh[n]*dinv[n]^2 + b )
// ---------------------------------------------------------------------------
__global__ __launch_bounds__(256) void k_pull(const uint4* __restrict__ xwh,
                                              const int* __restrict__ row_start,
                                              const int* __restrict__ count,
                                              const int* __restrict__ csr,
                                              const float* __restrict__ dinv,
                                              const float* __restrict__ b,
                                              uint4* __restrict__ h16) {
    int gid = blockIdx.x * 256 + threadIdx.x;
    int n = gid >> 4;
    int q = gid & 15;
    if (n >= N_NODES) return;

    float di = dinv[n];
    float s = di * di;
    float a[8];
    {
        uint4 sv = xwh[(size_t)n * 16 + q];
        float lo, hi;
        bf2x(sv.x, lo, hi); a[0] = lo * s; a[1] = hi * s;
        bf2x(sv.y, lo, hi); a[2] = lo * s; a[3] = hi * s;
        bf2x(sv.z, lo, hi); a[4] = lo * s; a[5] = hi * s;
        bf2x(sv.w, lo, hi); a[6] = lo * s; a[7] = hi * s;
    }

    int beg = row_start[n];
    int end = beg + count[n];
    for (int i = beg; i < end; ++i) {
        int src = csr[i];
        float nv = dinv[src] * di;
        uint4 m = xwh[(size_t)src * 16 + q];
        float lo, hi;
        bf2x(m.x, lo, hi); a[0] += lo * nv; a[1] += hi * nv;
        bf2x(m.y, lo, hi); a[2] += lo * nv; a[3] += hi * nv;
        bf2x(m.z, lo, hi); a[4] += lo * nv; a[5] += hi * nv;
        bf2x(m.w, lo, hi); a[6] += lo * nv; a[7] += hi * nv;
    }

    const float4* b4 = (const float4*)b;
    float4 b0 = b4[2 * q], b1 = b4[2 * q + 1];
    a[0] += b0.x; a[1] += b0.y; a[2] += b0.z; a[3] += b0.w;
    a[4] += b1.x; a[5] += b1.y; a[6] += b1.z; a[7] += b1.w;

    uint4 o;
    o.x = pack2(a[0], a[1]);
    o.y = pack2(a[2], a[3]);
    o.z = pack2(a[4], a[5]);
    o.w = pack2(a[6], a[7]);
    h16[(size_t)n * 16 + q] = o;
}

// ---------------------------------------------------------------------------
// K6: link head. 32 lanes per label edge (lanes 0-15 drug row, 16-31 prot row,
//     8 bf16 cols/lane). W_lin rows cached in REGISTERS, amortized via
//     grid-stride loop. Butterfly reduce over the 32-lane group sums
//     drug+prot halves in one go.
// ---------------------------------------------------------------------------
__global__ __launch_bounds__(256) void k_link(const int* __restrict__ eli,
                                              const uint4* __restrict__ h16,
                                              const float* __restrict__ Wg,
                                              const float* __restrict__ bl,
                                              float* __restrict__ out) {
    __shared__ float Wl[2 * HID * OUT];  // 1280 floats
    __shared__ float bls[OUT];
    const int tid = threadIdx.x;
    for (int i = tid; i < 2 * HID * OUT; i += 256) Wl[i] = Wg[i];
    if (tid < OUT) bls[tid] = bl[tid];
    __syncthreads();

    const int lane = tid & 31;
    const int half = lane >> 4;          // 0 = drug, 1 = prot
    const int q = lane & 15;             // 8-col chunk within row
    // cache this lane's 8 W rows (40 floats) in registers
    float w[8][OUT];
    const int rbase = half * HID + q * 8;
#pragma unroll
    for (int j = 0; j < 8; ++j)
#pragma unroll
        for (int o = 0; o < OUT; ++o) w[j][o] = Wl[(rbase + j) * OUT + o];

    const int grp = (blockIdx.x * 256 + tid) >> 5;
    const int ngrp = gridDim.x * 8;

    for (int l = grp; l < N_LABEL; l += ngrp) {
        int idx = eli[half * N_LABEL + l];
        uint4 hv = h16[(size_t)idx * 16 + q];
        float f[8];
        bf2x(hv.x, f[0], f[1]);
        bf2x(hv.y, f[2], f[3]);
        bf2x(hv.z, f[4], f[5]);
        bf2x(hv.w, f[6], f[7]);

        float acc[OUT] = {0.f, 0.f, 0.f, 0.f, 0.f};
#pragma unroll
        for (int j = 0; j < 8; ++j)
#pragma unroll
            for (int o = 0; o < OUT; ++o) acc[o] += f[j] * w[j][o];

#pragma unroll
        for (int o = 0; o < OUT; ++o) {
            float a = acc[o];
#pragma unroll
            for (int off = 1; off <= 16; off <<= 1) a += __shfl_xor(a, off);
            acc[o] = a;
        }
        if (lane == 0) {
#pragma unroll
            for (int o = 0; o < OUT; ++o) out[(size_t)l * OUT + o] = acc[o] + bls[o];
        }
    }
}

// ---------------------------------------------------------------------------
extern "C" void kernel_launch(void* const* d_in, const int* in_sizes, int n_in,
                              void* d_out, int out_size, void* d_ws, size_t ws_size,
                              hipStream_t stream) {
    const float* x     = (const float*)d_in[0];
    const int*   ei    = (const int*)d_in[1];
    const int*   eli   = (const int*)d_in[2];
    const float* W_gcn = (const float*)d_in[3];
    const float* b_gcn = (const float*)d_in[4];
    const float* W_lin = (const float*)d_in[5];
    const float* b_lin = (const float*)d_in[6];
    float* out = (float*)d_out;

    // workspace layout (bf16 buffers stored as unsigned words)
    unsigned* xwh     = (unsigned*)d_ws;                       // 6.4M uints (25.6 MB)
    unsigned* h16     = xwh + (size_t)N_NODES * HID / 2;       // 6.4M uints (25.6 MB)
    float* dinv       = (float*)(h16 + (size_t)N_NODES * HID / 2);  // 100k floats
    int*   count      = (int*)(dinv + N_NODES);                // 100k ints
    int*   cursor     = count + N_NODES;                       // 100k ints
    int*   row_start  = cursor + N_NODES;                      // 100k ints
    int*   total      = row_start + N_NODES;                   // 1 int (+3 pad)
    int*   csr        = total + 4;                             // 1.6M ints (6.4 MB)

    hipMemsetAsync(count, 0, N_NODES * sizeof(int), stream);
    hipMemsetAsync(total, 0, sizeof(int), stream);

    // K1: xwh = bf16(x @ W_gcn)
    k_gemm<<<1000, 256, 0, stream>>>(x, W_gcn, xwh);
    // K2: in-degree count (int atomics)
    k_count<<<(N_EDGES + 255) / 256, 256, 0, stream>>>(ei, count);
    // K3: CSR range allocation + dinv + cursor reset
    k_alloc<<<(N_NODES + 255) / 256, 256, 0, stream>>>(count, row_start, cursor, dinv, total);
    // K4: CSR fill
    k_fill<<<(N_EDGES + 255) / 256, 256, 0, stream>>>(ei, row_start, cursor, csr);
    // K5: pull aggregation (bf16 messages, self-loop + bias fused)
    k_pull<<<(N_NODES * 16 + 255) / 256, 256, 0, stream>>>((const uint4*)xwh, row_start, count,
                                                           csr, dinv, b_gcn, (uint4*)h16);
    // K6: link prediction head (W in registers, grid-stride)
    k_link<<<2048, 256, 0, stream>>>(eli, (const uint4*)h16, W_lin, b_lin, out);
}

// Round 5
// 261.808 us; speedup vs baseline: 11.3150x; 1.4188x over previous
//
#include <hip/hip_runtime.h>

#define N_NODES 100000
#define N_EDGES 1600000
#define N_LABEL 200000
#define HID 128
#define OUT 5

typedef __attribute__((ext_vector_type(8))) short bf16x8;
typedef __attribute__((ext_vector_type(4))) float f32x4;

// ---- bf16 helpers (manual, RNE) -------------------------------------------
__device__ inline void bf2x(unsigned u, float& lo, float& hi) {
    lo = __uint_as_float(u << 16);
    hi = __uint_as_float(u & 0xffff0000u);
}
__device__ inline unsigned pack2(float a, float b) {
    unsigned ua = __float_as_uint(a), ub = __float_as_uint(b);
    ua = (ua + 0x7fffu + ((ua >> 16) & 1u)) >> 16;
    ub = (ub + 0x7fffu + ((ub >> 16) & 1u)) & 0xffff0000u;
    return ua | ub;
}
__device__ inline unsigned short bf1(float f) {
    unsigned u = __float_as_uint(f);
    return (unsigned short)((u + 0x7fffu + ((u >> 16) & 1u)) >> 16);
}

// ---------------------------------------------------------------------------
// K0: wt[n][k] = bf16(W[k][n])  (transpose + convert, one-time 64KB)
// ---------------------------------------------------------------------------
__global__ void k_prep(const float* __restrict__ Wg, unsigned short* __restrict__ wt) {
    int n = blockIdx.x;   // 128 blocks
    int k = threadIdx.x;  // 128 threads
    wt[n * HID + k] = bf1(Wg[k * HID + n]);
}

// ---------------------------------------------------------------------------
// K1: xwh = bf16(x @ W) via MFMA 16x16x32 bf16.
//     64-row tiles, 4 waves; x and W^T staged in XOR-swizzled bf16 LDS
//     (byte ^= (row&7)<<4 breaks the stride-256B bank conflict).
//     Fragment maps: A row=l&15 k=(l>>4)*8+j; B col=l&15 same k;
//     D col=l&15, row=(l>>4)*4+reg  [HW-verified layout].
// ---------------------------------------------------------------------------
__global__ __launch_bounds__(256) void k_gemm(const float* __restrict__ x,
                                              const unsigned short* __restrict__ wt,
                                              unsigned short* __restrict__ xwh) {
    __shared__ char sm[49152];  // xs bf16[64][128] @0 (16KB); Wt bf16[128][128] @16384 (32KB)
    const int tid = threadIdx.x;
    const int r0 = blockIdx.x * 64;

    {   // stage W^T: 2048 uint4, 8 per thread, coalesced
        const uint4* w4 = (const uint4*)wt;
#pragma unroll
        for (int i = 0; i < 8; ++i) {
            int f = i * 256 + tid;
            int n = f >> 4;        // row 0..127
            int kq = f & 15;       // 16B chunk
            uint4 v = w4[f];
            *(uint4*)(sm + 16384 + n * 256 + ((kq * 16) ^ ((n & 7) << 4))) = v;
        }
    }
    {   // stage x tile -> bf16: 2048 float4, 8 per thread
        const float4* x4 = (const float4*)x;
#pragma unroll
        for (int i = 0; i < 8; ++i) {
            int f = i * 256 + tid;
            int row = f >> 5;      // 32 float4 per row
            int kq = f & 31;
            int grow = r0 + row;
            float4 gv;
            if (grow < N_NODES) gv = x4[(size_t)grow * 32 + kq];
            else { gv.x = 0.f; gv.y = 0.f; gv.z = 0.f; gv.w = 0.f; }
            uint2 p;
            p.x = pack2(gv.x, gv.y);
            p.y = pack2(gv.z, gv.w);
            *(uint2*)(sm + row * 256 + ((kq * 8) ^ ((row & 7) << 4))) = p;
        }
    }
    __syncthreads();

    const int w = tid >> 6;   // wave id: rows w*16..w*16+15 of tile
    const int l = tid & 63;
    const int lm = l & 15;
    const int g = l >> 4;

    bf16x8 a[4];
#pragma unroll
    for (int kc = 0; kc < 4; ++kc) {
        int row = w * 16 + lm;
        int kb = kc * 64 + g * 16;
        a[kc] = *(const bf16x8*)(sm + row * 256 + (kb ^ ((row & 7) << 4)));
    }

    f32x4 accs[8];
#pragma unroll
    for (int nt = 0; nt < 8; ++nt) accs[nt] = (f32x4){0.f, 0.f, 0.f, 0.f};

#pragma unroll
    for (int nt = 0; nt < 8; ++nt) {
        int n = nt * 16 + lm;
        const char* bp = sm + 16384 + n * 256;
        int msk = (n & 7) << 4;
#pragma unroll
        for (int kc = 0; kc < 4; ++kc) {
            int kb = kc * 64 + g * 16;
            bf16x8 b = *(const bf16x8*)(bp + (kb ^ msk));
            accs[nt] = __builtin_amdgcn_mfma_f32_16x16x32_bf16(a[kc], b, accs[nt], 0, 0, 0);
        }
    }

#pragma unroll
    for (int nt = 0; nt < 8; ++nt) {
        int col = nt * 16 + lm;
#pragma unroll
        for (int r = 0; r < 4; ++r) {
            int row = r0 + w * 16 + g * 4 + r;
            if (row < N_NODES) xwh[(size_t)row * HID + col] = bf1(accs[nt][r]);
        }
    }
}

// ---------------------------------------------------------------------------
// K2: rank pass: rank[e] = count[dst]++ (int atomics; rank write coalesced)
// ---------------------------------------------------------------------------
__global__ void k_rank(const int* __restrict__ ei, int* __restrict__ count,
                       int* __restrict__ rank) {
    int e = blockIdx.x * 256 + threadIdx.x;
    if (e < N_EDGES) rank[e] = atomicAdd(&count[ei[N_EDGES + e]], 1);
}

// ---------------------------------------------------------------------------
// K3: CSR range allocator — buckets disjoint, not globally ordered.
// ---------------------------------------------------------------------------
__global__ __launch_bounds__(256) void k_alloc(const int* __restrict__ count,
                                               int* __restrict__ row_start,
                                               float* __restrict__ dinv,
                                               int* __restrict__ total) {
    __shared__ int smem[256];
    __shared__ int base;
    const int t = threadIdx.x;
    const int i = blockIdx.x * 256 + t;
    int c = (i < N_NODES) ? count[i] : 0;
    smem[t] = c;
    __syncthreads();
#pragma unroll
    for (int off = 1; off < 256; off <<= 1) {
        int v = (t >= off) ? smem[t - off] : 0;
        __syncthreads();
        smem[t] += v;
        __syncthreads();
    }
    if (t == 255) base = atomicAdd(total, smem[255]);
    int incl = smem[t];
    __syncthreads();
    if (i < N_NODES) {
        row_start[i] = base + incl - c;
        dinv[i] = rsqrtf((float)(c + 1));
    }
}

// ---------------------------------------------------------------------------
// K4: fill CSR (no atomics): csr[row_start[dst] + rank[e]] = src
// ---------------------------------------------------------------------------
__global__ void k_fill(const int* __restrict__ ei, const int* __restrict__ row_start,
                       const int* __restrict__ rank, int* __restrict__ csr) {
    int e = blockIdx.x * 256 + threadIdx.x;
    if (e < N_EDGES) {
        int dst = ei[N_EDGES + e];
        csr[row_start[dst] + rank[e]] = ei[e];
    }
}

// ---------------------------------------------------------------------------
// K5: pull-aggregate (bf16 messages, fp32 accum). 16 lanes/node, 8 bf16/lane.
// ---------------------------------------------------------------------------
__global__ __launch_bounds__(256) void k_pull(const uint4* __restrict__ xwh,
                                              const int* __restrict__ row_start,
                                              const int* __restrict__ count,
                                              const int* __restrict__ csr,
                                              const float* __restrict__ dinv,
                                              const float* __restrict__ b,
                                              uint4* __restrict__ h16) {
    int gid = blockIdx.x * 256 + threadIdx.x;
    int n = gid >> 4;
    int q = gid & 15;
    if (n >= N_NODES) return;

    float di = dinv[n];
    float s = di * di;
    float a[8];
    {
        uint4 sv = xwh[(size_t)n * 16 + q];
        float lo, hi;
        bf2x(sv.x, lo, hi); a[0] = lo * s; a[1] = hi * s;
        bf2x(sv.y, lo, hi); a[2] = lo * s; a[3] = hi * s;
        bf2x(sv.z, lo, hi); a[4] = lo * s; a[5] = hi * s;
        bf2x(sv.w, lo, hi); a[6] = lo * s; a[7] = hi * s;
    }

    int beg = row_start[n];
    int end = beg + count[n];
    for (int i = beg; i < end; ++i) {
        int src = csr[i];
        float nv = dinv[src] * di;
        uint4 m = xwh[(size_t)src * 16 + q];
        float lo, hi;
        bf2x(m.x, lo, hi); a[0] += lo * nv; a[1] += hi * nv;
        bf2x(m.y, lo, hi); a[2] += lo * nv; a[3] += hi * nv;
        bf2x(m.z, lo, hi); a[4] += lo * nv; a[5] += hi * nv;
        bf2x(m.w, lo, hi); a[6] += lo * nv; a[7] += hi * nv;
    }

    const float4* b4 = (const float4*)b;
    float4 b0 = b4[2 * q], b1 = b4[2 * q + 1];
    a[0] += b0.x; a[1] += b0.y; a[2] += b0.z; a[3] += b0.w;
    a[4] += b1.x; a[5] += b1.y; a[6] += b1.z; a[7] += b1.w;

    uint4 o;
    o.x = pack2(a[0], a[1]);
    o.y = pack2(a[2], a[3]);
    o.z = pack2(a[4], a[5]);
    o.w = pack2(a[6], a[7]);
    h16[(size_t)n * 16 + q] = o;
}

// ---------------------------------------------------------------------------
// K6: link head. 32 lanes per label edge; W_lin rows in registers.
// ---------------------------------------------------------------------------
__global__ __launch_bounds__(256) void k_link(const int* __restrict__ eli,
                                              const uint4* __restrict__ h16,
                                              const float* __restrict__ Wg,
                                              const float* __restrict__ bl,
                                              float* __restrict__ out) {
    __shared__ float Wl[2 * HID * OUT];
    __shared__ float bls[OUT];
    const int tid = threadIdx.x;
    for (int i = tid; i < 2 * HID * OUT; i += 256) Wl[i] = Wg[i];
    if (tid < OUT) bls[tid] = bl[tid];
    __syncthreads();

    const int lane = tid & 31;
    const int half = lane >> 4;
    const int q = lane & 15;
    float w[8][OUT];
    const int rbase = half * HID + q * 8;
#pragma unroll
    for (int j = 0; j < 8; ++j)
#pragma unroll
        for (int o = 0; o < OUT; ++o) w[j][o] = Wl[(rbase + j) * OUT + o];

    const int grp = (blockIdx.x * 256 + tid) >> 5;
    const int ngrp = gridDim.x * 8;

    for (int l = grp; l < N_LABEL; l += ngrp) {
        int idx = eli[half * N_LABEL + l];
        uint4 hv = h16[(size_t)idx * 16 + q];
        float f[8];
        bf2x(hv.x, f[0], f[1]);
        bf2x(hv.y, f[2], f[3]);
        bf2x(hv.z, f[4], f[5]);
        bf2x(hv.w, f[6], f[7]);

        float acc[OUT] = {0.f, 0.f, 0.f, 0.f, 0.f};
#pragma unroll
        for (int j = 0; j < 8; ++j)
#pragma unroll
            for (int o = 0; o < OUT; ++o) acc[o] += f[j] * w[j][o];

#pragma unroll
        for (int o = 0; o < OUT; ++o) {
            float a = acc[o];
#pragma unroll
            for (int off = 1; off <= 16; off <<= 1) a += __shfl_xor(a, off);
            acc[o] = a;
        }
        if (lane == 0) {
#pragma unroll
            for (int o = 0; o < OUT; ++o) out[(size_t)l * OUT + o] = acc[o] + bls[o];
        }
    }
}

// ---------------------------------------------------------------------------
extern "C" void kernel_launch(void* const* d_in, const int* in_sizes, int n_in,
                              void* d_out, int out_size, void* d_ws, size_t ws_size,
                              hipStream_t stream) {
    const float* x     = (const float*)d_in[0];
    const int*   ei    = (const int*)d_in[1];
    const int*   eli   = (const int*)d_in[2];
    const float* W_gcn = (const float*)d_in[3];
    const float* b_gcn = (const float*)d_in[4];
    const float* W_lin = (const float*)d_in[5];
    const float* b_lin = (const float*)d_in[6];
    float* out = (float*)d_out;

    // workspace layout
    unsigned short* xwh = (unsigned short*)d_ws;               // 12.8M u16 (25.6 MB)
    unsigned short* h16 = xwh + (size_t)N_NODES * HID;         // 12.8M u16 (25.6 MB)
    float* dinv      = (float*)(h16 + (size_t)N_NODES * HID);  // 100k f32
    int*   count     = (int*)(dinv + N_NODES);                 // 100k int
    int*   rank      = count + N_NODES;                        // 1.6M int
    int*   row_start = rank + N_EDGES;                         // 100k int
    int*   total     = row_start + N_NODES;                    // 1 int (+3 pad)
    unsigned short* wt = (unsigned short*)(total + 4);         // 16384 u16 (32KB)
    int*   csr       = (int*)(wt + HID * HID);                 // 1.6M int

    hipMemsetAsync(count, 0, N_NODES * sizeof(int), stream);
    hipMemsetAsync(total, 0, sizeof(int), stream);

    // K0: W^T -> bf16
    k_prep<<<HID, HID, 0, stream>>>(W_gcn, wt);
    // K1: xwh = bf16(x @ W_gcn) via MFMA
    k_gemm<<<(N_NODES + 63) / 64, 256, 0, stream>>>(x, wt, xwh);
    // K2: in-degree count + per-edge rank
    k_rank<<<(N_EDGES + 255) / 256, 256, 0, stream>>>(ei, count, rank);
    // K3: CSR range allocation + dinv
    k_alloc<<<(N_NODES + 255) / 256, 256, 0, stream>>>(count, row_start, dinv, total);
    // K4: CSR fill (atomic-free)
    k_fill<<<(N_EDGES + 255) / 256, 256, 0, stream>>>(ei, row_start, rank, csr);
    // K5: pull aggregation (bf16 messages, self-loop + bias fused)
    k_pull<<<(N_NODES * 16 + 255) / 256, 256, 0, stream>>>((const uint4*)xwh, row_start, count,
                                                           csr, dinv, b_gcn, (uint4*)h16);
    // K6: link prediction head
    k_link<<<2048, 256, 0, stream>>>(eli, (const uint4*)h16, W_lin, b_lin, out);
}

// Round 6
// 253.730 us; speedup vs baseline: 11.6752x; 1.0318x over previous
//
#include <hip/hip_runtime.h>

#define N_NODES 100000
#define N_EDGES 1600000
#define N_LABEL 200000
#define HID 128
#define OUT 5

typedef __attribute__((ext_vector_type(8))) short bf16x8;
typedef __attribute__((ext_vector_type(4))) float f32x4;

// ---- bf16 helpers (manual, RNE) -------------------------------------------
__device__ inline void bf2x(unsigned u, float& lo, float& hi) {
    lo = __uint_as_float(u << 16);
    hi = __uint_as_float(u & 0xffff0000u);
}
__device__ inline unsigned pack2(float a, float b) {
    unsigned ua = __float_as_uint(a), ub = __float_as_uint(b);
    ua = (ua + 0x7fffu + ((ua >> 16) & 1u)) >> 16;
    ub = (ub + 0x7fffu + ((ub >> 16) & 1u)) & 0xffff0000u;
    return ua | ub;
}
__device__ inline unsigned short bf1(float f) {
    unsigned u = __float_as_uint(f);
    return (unsigned short)((u + 0x7fffu + ((u >> 16) & 1u)) >> 16);
}

// ---------------------------------------------------------------------------
// K0: wt[n][k] = bf16(W[k][n])  (transpose + convert, one-time 64KB)
// ---------------------------------------------------------------------------
__global__ void k_prep(const float* __restrict__ Wg, unsigned short* __restrict__ wt) {
    int n = blockIdx.x;   // 128 blocks
    int k = threadIdx.x;  // 128 threads
    wt[n * HID + k] = bf1(Wg[k * HID + n]);
}

// ---------------------------------------------------------------------------
// K1: xwh = bf16( (x @ W) * dinv[row] )  via MFMA 16x16x32 bf16.
//     PRE-SCALED by dinv so the pull loop is pure adds.
//     64-row tiles, 4 waves; x and W^T staged in XOR-swizzled bf16 LDS.
// ---------------------------------------------------------------------------
__global__ __launch_bounds__(256) void k_gemm(const float* __restrict__ x,
                                              const unsigned short* __restrict__ wt,
                                              const float* __restrict__ dinv,
                                              unsigned short* __restrict__ xwh) {
    __shared__ char sm[49152];  // xs bf16[64][128] @0 (16KB); Wt bf16[128][128] @16384 (32KB)
    const int tid = threadIdx.x;
    const int r0 = blockIdx.x * 64;

    {   // stage W^T: 2048 uint4, 8 per thread, coalesced
        const uint4* w4 = (const uint4*)wt;
#pragma unroll
        for (int i = 0; i < 8; ++i) {
            int f = i * 256 + tid;
            int n = f >> 4;        // row 0..127
            int kq = f & 15;       // 16B chunk
            uint4 v = w4[f];
            *(uint4*)(sm + 16384 + n * 256 + ((kq * 16) ^ ((n & 7) << 4))) = v;
        }
    }
    {   // stage x tile -> bf16: 2048 float4, 8 per thread
        const float4* x4 = (const float4*)x;
#pragma unroll
        for (int i = 0; i < 8; ++i) {
            int f = i * 256 + tid;
            int row = f >> 5;      // 32 float4 per row
            int kq = f & 31;
            int grow = r0 + row;
            float4 gv;
            if (grow < N_NODES) gv = x4[(size_t)grow * 32 + kq];
            else { gv.x = 0.f; gv.y = 0.f; gv.z = 0.f; gv.w = 0.f; }
            uint2 p;
            p.x = pack2(gv.x, gv.y);
            p.y = pack2(gv.z, gv.w);
            *(uint2*)(sm + row * 256 + ((kq * 8) ^ ((row & 7) << 4))) = p;
        }
    }
    __syncthreads();

    const int w = tid >> 6;   // wave id: rows w*16..w*16+15 of tile
    const int l = tid & 63;
    const int lm = l & 15;
    const int g = l >> 4;

    bf16x8 a[4];
#pragma unroll
    for (int kc = 0; kc < 4; ++kc) {
        int row = w * 16 + lm;
        int kb = kc * 64 + g * 16;
        a[kc] = *(const bf16x8*)(sm + row * 256 + (kb ^ ((row & 7) << 4)));
    }

    f32x4 accs[8];
#pragma unroll
    for (int nt = 0; nt < 8; ++nt) accs[nt] = (f32x4){0.f, 0.f, 0.f, 0.f};

#pragma unroll
    for (int nt = 0; nt < 8; ++nt) {
        int n = nt * 16 + lm;
        const char* bp = sm + 16384 + n * 256;
        int msk = (n & 7) << 4;
#pragma unroll
        for (int kc = 0; kc < 4; ++kc) {
            int kb = kc * 64 + g * 16;
            bf16x8 b = *(const bf16x8*)(bp + (kb ^ msk));
            accs[nt] = __builtin_amdgcn_mfma_f32_16x16x32_bf16(a[kc], b, accs[nt], 0, 0, 0);
        }
    }

    float dv[4];
#pragma unroll
    for (int r = 0; r < 4; ++r) {
        int row = r0 + w * 16 + g * 4 + r;
        dv[r] = (row < N_NODES) ? dinv[row] : 0.f;
    }

#pragma unroll
    for (int nt = 0; nt < 8; ++nt) {
        int col = nt * 16 + lm;
#pragma unroll
        for (int r = 0; r < 4; ++r) {
            int row = r0 + w * 16 + g * 4 + r;
            if (row < N_NODES) xwh[(size_t)row * HID + col] = bf1(accs[nt][r] * dv[r]);
        }
    }
}

// ---------------------------------------------------------------------------
// K2: rank pass: rank[e] = count[dst]++ (int atomics; rank write coalesced)
// ---------------------------------------------------------------------------
__global__ void k_rank(const int* __restrict__ ei, int* __restrict__ count,
                       int* __restrict__ rank) {
    int e = blockIdx.x * 256 + threadIdx.x;
    if (e < N_EDGES) rank[e] = atomicAdd(&count[ei[N_EDGES + e]], 1);
}

// ---------------------------------------------------------------------------
// K3: CSR range allocator — buckets disjoint, not globally ordered.
// ---------------------------------------------------------------------------
__global__ __launch_bounds__(256) void k_alloc(const int* __restrict__ count,
                                               int* __restrict__ row_start,
                                               float* __restrict__ dinv,
                                               int* __restrict__ total) {
    __shared__ int smem[256];
    __shared__ int base;
    const int t = threadIdx.x;
    const int i = blockIdx.x * 256 + t;
    int c = (i < N_NODES) ? count[i] : 0;
    smem[t] = c;
    __syncthreads();
#pragma unroll
    for (int off = 1; off < 256; off <<= 1) {
        int v = (t >= off) ? smem[t - off] : 0;
        __syncthreads();
        smem[t] += v;
        __syncthreads();
    }
    if (t == 255) base = atomicAdd(total, smem[255]);
    int incl = smem[t];
    __syncthreads();
    if (i < N_NODES) {
        row_start[i] = base + incl - c;
        dinv[i] = rsqrtf((float)(c + 1));
    }
}

// ---------------------------------------------------------------------------
// K4: fill CSR (no atomics): csr[row_start[dst] + rank[e]] = src
// ---------------------------------------------------------------------------
__global__ void k_fill(const int* __restrict__ ei, const int* __restrict__ row_start,
                       const int* __restrict__ rank, int* __restrict__ csr) {
    int e = blockIdx.x * 256 + threadIdx.x;
    if (e < N_EDGES) {
        int dst = ei[N_EDGES + e];
        csr[row_start[dst] + rank[e]] = ei[e];
    }
}

// ---------------------------------------------------------------------------
// K5: pull-aggregate v2. ONE WAVE per node (64 lanes x 1 dword = 256B row):
//     zero divergence (trip == deg), wave-uniform csr -> scalar loads,
//     4x unrolled gathers for MLP. Messages are pre-scaled by dinv[src];
//     edge loop is pure adds; final scale by dinv[n].
// ---------------------------------------------------------------------------
__global__ __launch_bounds__(256) void k_pull(const unsigned* __restrict__ xwp,
                                              const int* __restrict__ row_start,
                                              const int* __restrict__ count,
                                              const int* __restrict__ csr,
                                              const float* __restrict__ dinv,
                                              const float* __restrict__ b,
                                              unsigned* __restrict__ h16) {
    int gid = blockIdx.x * 256 + threadIdx.x;
    int n = gid >> 6;          // one wave per node
    int c = gid & 63;          // dword lane (2 bf16 cols: 2c, 2c+1)
    if (n >= N_NODES) return;

    float aLo, aHi;
    {   // self term: xwh already carries dinv[n]
        unsigned sv = xwp[(size_t)n * 64 + c];
        bf2x(sv, aLo, aHi);
    }

    const int beg = row_start[n];
    const int end = beg + count[n];
    int i = beg;
    const int endu = beg + ((end - beg) & ~3);
    for (; i < endu; i += 4) {
        int s0 = csr[i], s1 = csr[i + 1], s2 = csr[i + 2], s3 = csr[i + 3];
        unsigned m0 = xwp[(size_t)s0 * 64 + c];
        unsigned m1 = xwp[(size_t)s1 * 64 + c];
        unsigned m2 = xwp[(size_t)s2 * 64 + c];
        unsigned m3 = xwp[(size_t)s3 * 64 + c];
        float lo, hi;
        bf2x(m0, lo, hi); aLo += lo; aHi += hi;
        bf2x(m1, lo, hi); aLo += lo; aHi += hi;
        bf2x(m2, lo, hi); aLo += lo; aHi += hi;
        bf2x(m3, lo, hi); aLo += lo; aHi += hi;
    }
    for (; i < end; ++i) {
        unsigned m = xwp[(size_t)csr[i] * 64 + c];
        float lo, hi;
        bf2x(m, lo, hi); aLo += lo; aHi += hi;
    }

    float di = dinv[n];
    float2 bv = ((const float2*)b)[c];
    h16[(size_t)n * 64 + c] = pack2(aLo * di + bv.x, aHi * di + bv.y);
}

// ---------------------------------------------------------------------------
// K6: link head. 32 lanes per label edge; W_lin rows in registers.
// ---------------------------------------------------------------------------
__global__ __launch_bounds__(256) void k_link(const int* __restrict__ eli,
                                              const uint4* __restrict__ h16,
                                              const float* __restrict__ Wg,
                                              const float* __restrict__ bl,
                                              float* __restrict__ out) {
    __shared__ float Wl[2 * HID * OUT];
    __shared__ float bls[OUT];
    const int tid = threadIdx.x;
    for (int i = tid; i < 2 * HID * OUT; i += 256) Wl[i] = Wg[i];
    if (tid < OUT) bls[tid] = bl[tid];
    __syncthreads();

    const int lane = tid & 31;
    const int half = lane >> 4;
    const int q = lane & 15;
    float w[8][OUT];
    const int rbase = half * HID + q * 8;
#pragma unroll
    for (int j = 0; j < 8; ++j)
#pragma unroll
        for (int o = 0; o < OUT; ++o) w[j][o] = Wl[(rbase + j) * OUT + o];

    const int grp = (blockIdx.x * 256 + tid) >> 5;
    const int ngrp = gridDim.x * 8;

    for (int l = grp; l < N_LABEL; l += ngrp) {
        int idx = eli[half * N_LABEL + l];
        uint4 hv = h16[(size_t)idx * 16 + q];
        float f[8];
        bf2x(hv.x, f[0], f[1]);
        bf2x(hv.y, f[2], f[3]);
        bf2x(hv.z, f[4], f[5]);
        bf2x(hv.w, f[6], f[7]);

        float acc[OUT] = {0.f, 0.f, 0.f, 0.f, 0.f};
#pragma unroll
        for (int j = 0; j < 8; ++j)
#pragma unroll
            for (int o = 0; o < OUT; ++o) acc[o] += f[j] * w[j][o];

#pragma unroll
        for (int o = 0; o < OUT; ++o) {
            float a = acc[o];
#pragma unroll
            for (int off = 1; off <= 16; off <<= 1) a += __shfl_xor(a, off);
            acc[o] = a;
        }
        if (lane == 0) {
#pragma unroll
            for (int o = 0; o < OUT; ++o) out[(size_t)l * OUT + o] = acc[o] + bls[o];
        }
    }
}

// ---------------------------------------------------------------------------
extern "C" void kernel_launch(void* const* d_in, const int* in_sizes, int n_in,
                              void* d_out, int out_size, void* d_ws, size_t ws_size,
                              hipStream_t stream) {
    const float* x     = (const float*)d_in[0];
    const int*   ei    = (const int*)d_in[1];
    const int*   eli   = (const int*)d_in[2];
    const float* W_gcn = (const float*)d_in[3];
    const float* b_gcn = (const float*)d_in[4];
    const float* W_lin = (const float*)d_in[5];
    const float* b_lin = (const float*)d_in[6];
    float* out = (float*)d_out;

    // workspace layout
    unsigned short* xwh = (unsigned short*)d_ws;               // 12.8M u16 (25.6 MB), pre-scaled by dinv
    unsigned short* h16 = xwh + (size_t)N_NODES * HID;         // 12.8M u16 (25.6 MB)
    float* dinv      = (float*)(h16 + (size_t)N_NODES * HID);  // 100k f32
    int*   count     = (int*)(dinv + N_NODES);                 // 100k int
    int*   rank      = count + N_NODES;                        // 1.6M int
    int*   row_start = rank + N_EDGES;                         // 100k int
    int*   total     = row_start + N_NODES;                    // 1 int (+3 pad)
    unsigned short* wt = (unsigned short*)(total + 4);         // 16384 u16 (32KB)
    int*   csr       = (int*)(wt + HID * HID);                 // 1.6M int

    hipMemsetAsync(count, 0, N_NODES * sizeof(int), stream);
    hipMemsetAsync(total, 0, sizeof(int), stream);

    // K0: W^T -> bf16
    k_prep<<<HID, HID, 0, stream>>>(W_gcn, wt);
    // K2: in-degree count + per-edge rank  (before gemm: gemm needs dinv)
    k_rank<<<(N_EDGES + 255) / 256, 256, 0, stream>>>(ei, count, rank);
    // K3: CSR range allocation + dinv
    k_alloc<<<(N_NODES + 255) / 256, 256, 0, stream>>>(count, row_start, dinv, total);
    // K1: xwh = bf16((x @ W_gcn) * dinv) via MFMA
    k_gemm<<<(N_NODES + 63) / 64, 256, 0, stream>>>(x, wt, dinv, xwh);
    // K4: CSR fill (atomic-free)
    k_fill<<<(N_EDGES + 255) / 256, 256, 0, stream>>>(ei, row_start, rank, csr);
    // K5: pull aggregation (1 wave/node, unrolled, pure adds)
    k_pull<<<(int)(((size_t)N_NODES * 64 + 255) / 256), 256, 0, stream>>>(
        (const unsigned*)xwh, row_start, count, csr, dinv, b_gcn, (unsigned*)h16);
    // K6: link prediction head
    k_link<<<2048, 256, 0, stream>>>(eli, (const uint4*)h16, W_lin, b_lin, out);
}